// Round 6
// baseline (376.411 us; speedup 1.0000x reference)
//
#include <hip/hip_runtime.h>
#include <hip/hip_bf16.h>

#define N_ROWS 4096
#define K_IN   8192
#define F_DIM  2048
#define GAMMA  (1.0f / 2048.0f)

typedef unsigned short u16;
typedef unsigned int   u32;
typedef unsigned char  u8;
typedef __attribute__((ext_vector_type(4))) int   i32x4;
typedef __attribute__((ext_vector_type(8))) int   i32x8;
typedef __attribute__((ext_vector_type(4))) float f32x4;
typedef __attribute__((ext_vector_type(2))) float f32x2;

// ---------------------------------------------------------------------------
// Fragment-major fp8 layout (validated R3/R4: zero bank conflicts in GEMM
// main loops). A [R][K] matrix is stored as 2KB sub-tiles:
//   off(r,k) = (rt*(K/128) + kt)*2048 + h*1024 + (16*q + rr)*16 + b
//   rt=r>>4, rr=r&15, kt=k>>7, q=(k>>5)&3, h=(k>>4)&1, b=k&15
// = exactly the mfma_scale_f32_16x16x128 operand order: lane (16q+rr) reads
// lo 16B at lane*16 and hi 16B at lane*16+1024 within a sub-tile. Staging is
// a LINEAR copy; every frag ds_read_b128 is 64 lanes x 16B contiguous.
// ---------------------------------------------------------------------------

__device__ __forceinline__ u32 pk4_fp8(float a, float b, float c, float d) {
  u32 u = 0;
  u = __builtin_amdgcn_cvt_pk_fp8_f32(a, b, u, false);
  u = __builtin_amdgcn_cvt_pk_fp8_f32(c, d, u, true);
  return u;
}
__device__ __forceinline__ u8 f8(float v) {
  return (u8)(__builtin_amdgcn_cvt_pk_fp8_f32(v, v, 0, false) & 0xff);
}

__device__ __forceinline__ void async16(const void* g, void* l) {
  __builtin_amdgcn_global_load_lds(
      (const __attribute__((address_space(1))) void*)g,
      (__attribute__((address_space(3))) void*)l, 16, 0, 0);
}

// ---------------- conversion kernels ----------------

// xs fp32 [4096][8192] -> fp8 fragment-major. One block = one 2KB sub-tile
// (16 rows x 128 k). Reads coalesced, writes contiguous 2KB.
__global__ void convert_xs(const float* __restrict__ xs, u8* __restrict__ out) {
  __shared__ float t16[16][132];   // +4 pad: stagger banks for the read phase
  const int bid = blockIdx.x;      // 0..16383
  const int rt = bid >> 6, kt = bid & 63;
  const int tid = threadIdx.x;     // 256
  const float* src = xs + (size_t)rt * 16 * K_IN + kt * 128;
#pragma unroll
  for (int j = 0; j < 2; ++j) {
    int i = tid + j * 256;         // 0..511 float4s
    int row = i >> 5, c4 = (i & 31) << 2;
    float4 v = *(const float4*)(src + (size_t)row * K_IN + c4);
    t16[row][c4 + 0] = v.x; t16[row][c4 + 1] = v.y;
    t16[row][c4 + 2] = v.z; t16[row][c4 + 3] = v.w;
  }
  __syncthreads();
  const int cw = tid >> 1, part = tid & 1;
  const int h = cw >> 6, l = cw & 63, q = l >> 4, rr = l & 15;
  const float* p = &t16[rr][q * 32 + h * 16 + part * 8];
  u32 u0 = pk4_fp8(p[0], p[1], p[2], p[3]);
  u32 u1 = pk4_fp8(p[4], p[5], p[6], p[7]);
  uint2 st = {u0, u1};
  *(uint2*)(out + ((size_t)(rt * 64 + kt) << 11) + cw * 16 + part * 8) = st;
}

// W [K_IN, F_DIM] fp32 -> Wt fragment-major [F_DIM rows, K_IN], scaled x64
// (w~0.011 would be subnormal in e4m3; 2^-6 undone via MFMA B-scale 121).
// Packed through LDS so global writes are contiguous 16B.
__global__ void transpose_w(const float* __restrict__ W, u8* __restrict__ Wt) {
  __shared__ float tile[128][33];
  __shared__ u32 ob[1024];         // 4KB packed output (2 sub-tiles)
  int k0 = blockIdx.x * 128;       // over K_IN/128
  int f0 = blockIdx.y * 32;        // over F_DIM/32
  int tx = threadIdx.x, ty = threadIdx.y;   // (32, 8)
#pragma unroll
  for (int kk = 0; kk < 16; ++kk) {
    int k = kk * 8 + ty;
    tile[k][tx] = 64.0f * W[(size_t)(k0 + k) * F_DIM + f0 + tx];
  }
  __syncthreads();
#pragma unroll
  for (int ff = 0; ff < 4; ++ff) {
    int f = ff * 8 + ty;
    int kk = tx * 4;
    u32 p = pk4_fp8(tile[kk][f], tile[kk + 1][f], tile[kk + 2][f], tile[kk + 3][f]);
    int rtl = f >> 4, rr = f & 15;
    int q = kk >> 5, hh = (kk >> 4) & 1;
    ob[rtl * 512 + hh * 256 + (q * 16 + rr) * 4 + ((kk & 15) >> 2)] = p;
  }
  __syncthreads();
  const int t = ty * 32 + tx;      // 0..255
  const int kt = k0 >> 7, rt0 = f0 >> 4;
  uint4* dst = (uint4*)(Wt + ((size_t)((rt0 + (t >> 7)) * 64 + kt) << 11));
  dst[t & 127] = ((const uint4*)ob)[t];
}

// beta[i] = alpha[i] * (2*y[i]-1); out[0] = -sum(alpha)
__global__ void prep(const float* __restrict__ alphas, const int* __restrict__ ys,
                     float* __restrict__ beta, float* __restrict__ out) {
  __shared__ float red[1024];
  int t = threadIdx.x;
  float s = 0.f;
  for (int i = t; i < N_ROWS; i += 1024) {
    float a = alphas[i];
    beta[i] = a * (float)(2 * ys[i] - 1);
    s += a;
  }
  red[t] = s;
  __syncthreads();
  for (int off = 512; off; off >>= 1) {
    if (t < off) red[t] += red[t + off];
    __syncthreads();
  }
  if (t == 0) out[0] = -red[0];
}

// sq[i] = sum_f dequant(X_fp8[i][f])^2 from the SAME quantized X the gram
// MFMA consumes (so d2_ii == 0 exactly). X is fragment-major [4096 r][2048 k].
__global__ void row_sq(const u32* __restrict__ X, float* __restrict__ sq) {
  int wave = threadIdx.x >> 6, lane = threadIdx.x & 63;
  int row = blockIdx.x * 4 + wave;
  const u8* base = (const u8*)X + ((size_t)(row >> 4) << 15);  // rt*16*2048
  const int rr = row & 15;
  float s = 0.f;
#pragma unroll
  for (int it = 0; it < 2; ++it) {
    int c = lane + it * 64;                 // 16B chunk id, 128 chunks/row
    int kt = c >> 3, q = (c >> 1) & 3, h = c & 1;
    uint4 v = *(const uint4*)(base + kt * 2048 + h * 1024 + (q * 16 + rr) * 16);
    u32 w[4] = {v.x, v.y, v.z, v.w};
#pragma unroll
    for (int p = 0; p < 4; ++p) {
      f32x2 lo = __builtin_amdgcn_cvt_pk_f32_fp8(w[p], false);
      f32x2 hi = __builtin_amdgcn_cvt_pk_f32_fp8(w[p], true);
      s += lo[0] * lo[0] + lo[1] * lo[1] + hi[0] * hi[0] + hi[1] * hi[1];
    }
  }
#pragma unroll
  for (int off = 32; off; off >>= 1) s += __shfl_down(s, off);
  if (lane == 0) sq[row] = s;
}

// ---- GEMM1: R1's 3-buffer-rotation schedule x fragment-major layout ----
// Tile 256x128, BK=128, 8 waves (4m x 2n), wave-tile 64x64, NO split-K (the
// conflicted merge epilogue is gone). Per iter: stage kt+2 issued FIRST
// (2-tile deadline, loads fly across 2 full iters), af/bg reads compiler-
// interleaved with the 16-MFMA cluster (no read-storm phase), counted
// vmcnt(6) + ONE barrier per K-tile. LDS 3x48KB = 144KB, grid 256 = 1/CU.
__global__ __launch_bounds__(512, 1) void gemm_xw(const u8* __restrict__ A,
                                                  const u8* __restrict__ Bt,
                                                  u8* __restrict__ X) {
  __shared__ __align__(16) u8 sA[3][32768];
  __shared__ __align__(16) u8 sB[3][16384];
  const int tid = threadIdx.x;
  // XCD-chunked swizzle: each XCD's 32 blocks cover 2 n-panels (2MB Wt ->
  // L2-resident) x all 16 m-tiles.
  const int wg = blockIdx.x;
  const int L = (wg & 7) * 32 + (wg >> 3);
  const int m0 = (L & 15) << 8;   // 16 m-tiles of 256
  const int n0 = (L >> 4) << 7;   // 16 n-tiles of 128

  const int lane = tid & 63;
  const int wave = tid >> 6;        // 0..7
  const int wm = (wave >> 1) << 6;  // 0,64,128,192
  const int wn = (wave & 1) << 6;   // 0,64

  // staging: A 32KB = 4 rounds, B 16KB = 2 rounds (512 thr x 16B, linear)
  const u8* pA[4]; const u8* pB[2];
#pragma unroll
  for (int j = 0; j < 4; ++j)
    pA[j] = A + (size_t)((m0 >> 4) + j * 4 + (tid >> 7)) * 131072 + (tid & 127) * 16;
#pragma unroll
  for (int j = 0; j < 2; ++j)
    pB[j] = Bt + (size_t)((n0 >> 4) + j * 4 + (tid >> 7)) * 131072 + (tid & 127) * 16;
  const int oT = (tid & 127) * 16 + ((tid >> 7) << 11);  // dest within buffer

  f32x4 acc[4][4];
  const f32x4 zero = {0.f, 0.f, 0.f, 0.f};
#pragma unroll
  for (int i = 0; i < 4; ++i)
#pragma unroll
    for (int j = 0; j < 4; ++j) acc[i][j] = zero;

#define STAGE(BUF, KT) { \
    _Pragma("unroll") for (int j_ = 0; j_ < 4; ++j_) \
      async16(pA[j_] + (size_t)(KT) * 2048, sA[BUF] + oT + j_ * 8192); \
    _Pragma("unroll") for (int j_ = 0; j_ < 2; ++j_) \
      async16(pB[j_] + (size_t)(KT) * 2048, sB[BUF] + oT + j_ * 8192); }
#define MFMA1(MT, NT, AF, BG) \
    acc[MT][NT] = __builtin_amdgcn_mfma_scale_f32_16x16x128_f8f6f4( \
        AF, BG, acc[MT][NT], 0, 0, 0, 127, 0, 121);

  // prologue: stage K-tiles 0 and 1 (12 loads), wait tile 0 (6 remain)
  STAGE(0, 0)
  STAGE(1, 1)
  asm volatile("s_waitcnt vmcnt(6)" ::: "memory");
  __builtin_amdgcn_s_barrier();

  const int aB = lane * 16;
  const int sa0 = wm >> 4;        // A sub base: 0,4,8,12
  const int sb0 = wn >> 4;        // B sub base: 0,4

  int cur = 0, nb = 2;
  for (int kt = 0; kt < 64; ++kt) {
    const bool st = (kt + 2 < 64);
    if (st) STAGE(nb, kt + 2)     // issue first: 2 full iters to land

    i32x8 af[4], bg[4];
#pragma unroll
    for (int mt = 0; mt < 4; ++mt) {
      const u8* b_ = sA[cur] + (sa0 + mt) * 2048 + aB;
      i32x4 lo = *(const i32x4*)(b_);
      i32x4 hi = *(const i32x4*)(b_ + 1024);
      af[mt] = (i32x8){lo[0], lo[1], lo[2], lo[3], hi[0], hi[1], hi[2], hi[3]};
    }
#pragma unroll
    for (int nt = 0; nt < 4; ++nt) {
      const u8* b_ = sB[cur] + (sb0 + nt) * 2048 + aB;
      i32x4 lo = *(const i32x4*)(b_);
      i32x4 hi = *(const i32x4*)(b_ + 1024);
      bg[nt] = (i32x8){lo[0], lo[1], lo[2], lo[3], hi[0], hi[1], hi[2], hi[3]};
    }
    __builtin_amdgcn_s_setprio(1);
#pragma unroll
    for (int mt = 0; mt < 4; ++mt)
#pragma unroll
      for (int nt = 0; nt < 4; ++nt)
        MFMA1(mt, nt, af[mt], bg[nt])
    __builtin_amdgcn_s_setprio(0);

    if (st) {
      asm volatile("s_waitcnt vmcnt(6)" ::: "memory");   // kt+1 landed
    } else if (kt < 63) {
      asm volatile("s_waitcnt vmcnt(0)" ::: "memory");   // tail
    }
    __builtin_amdgcn_s_barrier();
    cur = (cur == 2) ? 0 : cur + 1;
    nb  = (nb == 2) ? 0 : nb + 1;
  }
#undef STAGE
#undef MFMA1

  // epilogue: quantize + store fragment-major X (C/D: col=r, row=q*4+e)
  const int q = lane >> 4, r = lane & 15;
#pragma unroll
  for (int mt = 0; mt < 4; ++mt) {
#pragma unroll
    for (int nt = 0; nt < 4; ++nt) {
      const int rt_x = ((m0 + wm) >> 4) + mt;
      const int qx = (wn >> 5) + (nt >> 1);
      u8* dst = X + (size_t)(rt_x * 16 + (n0 >> 7)) * 2048 + (nt & 1) * 1024 + r;
#pragma unroll
      for (int e = 0; e < 4; ++e)
        dst[(qx * 16 + (q << 2) + e) * 16] = f8(acc[mt][nt][e]);
    }
  }
}

// ------- gram GEMM core on fragment-major X: 128x128 tile -------
// Pipelined: double-buffered A and B (64KB), stage kt+1 issued BEFORE the
// frag reads + MFMA cluster, ONE barrier per K-step (drains vmcnt).
__device__ __forceinline__ void gemm_tile_x(const u8* __restrict__ X, int m0, int n0,
                                            u8 (*sA)[16384], u8 (*sB)[16384],
                                            int tid, f32x4 acc[4][4]) {
  const int lane = tid & 63;
  const int wave = tid >> 6;
  const f32x4 zero = {0.f, 0.f, 0.f, 0.f};
#pragma unroll
  for (int mt = 0; mt < 4; ++mt)
#pragma unroll
    for (int nt = 0; nt < 4; ++nt) acc[mt][nt] = zero;

  // staging (linear copy; X sub-stride = 16*2048 = 32768, 16 k-tiles)
  const u8* pA = X + (size_t)((m0 >> 4) + (tid >> 7)) * 32768 + (tid & 127) * 16;
  const u8* pB = X + (size_t)((n0 >> 4) + (tid >> 7)) * 32768 + (tid & 127) * 16;
  const int oT = tid * 16;
  const int aB = lane * 16;
  const int sa0 = (wave >> 1) * 4, sb0 = (wave & 1) * 4;

#define STG(KT, BUF) { _Pragma("unroll") for (int j_ = 0; j_ < 4; ++j_) { \
    async16(pA + (size_t)j_ * 65536 + (size_t)(KT) * 2048, sA[BUF] + oT + j_ * 4096); \
    async16(pB + (size_t)j_ * 65536 + (size_t)(KT) * 2048, sB[BUF] + oT + j_ * 4096); } }

  STG(0, 0)
  __syncthreads();                // tile 0 visible

  for (int kt = 0; kt < 16; ++kt) {
    const int cur = kt & 1, nxt = cur ^ 1;
    if (kt < 15) STG(kt + 1, nxt)   // issue early: latency hidden under MFMA

    i32x8 af[4], bg[4];
#pragma unroll
    for (int mt = 0; mt < 4; ++mt) {
      const u8* b_ = sA[cur] + (sa0 + mt) * 2048 + aB;
      i32x4 lo = *(const i32x4*)(b_);
      i32x4 hi = *(const i32x4*)(b_ + 1024);
      af[mt] = (i32x8){lo[0], lo[1], lo[2], lo[3], hi[0], hi[1], hi[2], hi[3]};
    }
#pragma unroll
    for (int nt = 0; nt < 4; ++nt) {
      const u8* b_ = sB[cur] + (sb0 + nt) * 2048 + aB;
      i32x4 lo = *(const i32x4*)(b_);
      i32x4 hi = *(const i32x4*)(b_ + 1024);
      bg[nt] = (i32x8){lo[0], lo[1], lo[2], lo[3], hi[0], hi[1], hi[2], hi[3]};
    }
    __builtin_amdgcn_s_setprio(1);
#pragma unroll
    for (int mt = 0; mt < 4; ++mt)
#pragma unroll
      for (int nt = 0; nt < 4; ++nt)
        acc[mt][nt] = __builtin_amdgcn_mfma_scale_f32_16x16x128_f8f6f4(
            af[mt], bg[nt], acc[mt][nt], 0, 0, 0, 127, 0, 127);
    __builtin_amdgcn_s_setprio(0);
    __syncthreads();              // vmcnt(0): kt+1 landed; cur reads done
  }
#undef STG
}

// GEMM2 (triangular) + fused RBF epilogue + reduction
__global__ __launch_bounds__(256, 2) void gemm_kern(const u8* __restrict__ X,
                                                    const float* __restrict__ sq,
                                                    const float* __restrict__ beta,
                                                    float* __restrict__ out) {
  __shared__ __align__(16) u8 sA[2][16384];
  __shared__ __align__(16) u8 sB[2][16384];
  const int tid = threadIdx.x;
  int bid = blockIdx.x;
  int ib = 0;
  while (bid >= 32 - ib) { bid -= 32 - ib; ++ib; }
  const int jb = ib + bid;
  const int m0 = ib << 7;
  const int n0 = jb << 7;

  f32x4 acc[4][4];
  gemm_tile_x(X, m0, n0, sA, sB, tid, acc);

  const int lane = tid & 63;
  const int q = lane >> 4;
  const int r = lane & 15;
  const int wave = tid >> 6;
  const int wm = (wave >> 1) << 6;
  const int wn = (wave & 1) << 6;

  float sqj[4], bj[4];
#pragma unroll
  for (int nt = 0; nt < 4; ++nt) {
    int j = n0 + wn + (nt << 4) + r;
    sqj[nt] = sq[j];
    bj[nt] = beta[j];
  }
  float local = 0.f;
#pragma unroll
  for (int mt = 0; mt < 4; ++mt) {
#pragma unroll
    for (int e = 0; e < 4; ++e) {
      int i = m0 + wm + (mt << 4) + (q << 2) + e;
      float sqi = sq[i];
      float bi = beta[i];
#pragma unroll
      for (int nt = 0; nt < 4; ++nt) {
        float d2 = fmaxf(sqi + sqj[nt] - 2.f * acc[mt][nt][e], 0.f);
        local += bi * bj[nt] * __expf(-GAMMA * d2);
      }
    }
  }
  // diag blocks once (x0.5 for the 0.5*quad form), off-diag twice (x1.0)
  local *= (ib == jb) ? 0.5f : 1.0f;
#pragma unroll
  for (int off = 32; off; off >>= 1) local += __shfl_down(local, off);
  if (lane == 0) atomicAdd(out, local);
}

// ---------------- launch ----------------

extern "C" void kernel_launch(void* const* d_in, const int* in_sizes, int n_in,
                              void* d_out, int out_size, void* d_ws, size_t ws_size,
                              hipStream_t stream) {
  const float* xs = (const float*)d_in[0];
  const float* W = (const float*)d_in[1];
  const int* ys = (const int*)d_in[2];
  const float* alphas = (const float*)d_in[3];
  float* out = (float*)d_out;

  char* ws = (char*)d_ws;
  u8* xs_f8 = (u8*)ws;                        //  32 MB: [4096, 8192] fp8 frag-major
  u8* Wt_f8 = (u8*)(ws + 33554432);           //  16 MB: [2048, 8192] fp8 frag-major (x64)
  u8* X_f8  = (u8*)(ws + 50331648);           //   8 MB: [4096, 2048] fp8 frag-major
  float* sq   = (float*)(ws + 58720256);      //  16 KB
  float* beta = (float*)(ws + 58736640);      //  16 KB

  convert_xs<<<16384, 256, 0, stream>>>(xs, xs_f8);
  dim3 tb(32, 8);
  dim3 tg(K_IN / 128, F_DIM / 32);
  transpose_w<<<tg, tb, 0, stream>>>(W, Wt_f8);
  prep<<<1, 1024, 0, stream>>>(alphas, ys, beta, out);

  gemm_xw<<<256, 512, 0, stream>>>(xs_f8, Wt_f8, X_f8);
  row_sq<<<N_ROWS / 4, 256, 0, stream>>>((const u32*)X_f8, sq);
  gemm_kern<<<528, 256, 0, stream>>>(X_f8, sq, beta, out);
}

// Round 7
// 351.907 us; speedup vs baseline: 1.0696x; 1.0696x over previous
//
#include <hip/hip_runtime.h>
#include <hip/hip_bf16.h>

#define N_ROWS 4096
#define K_IN   8192
#define F_DIM  2048
#define GAMMA  (1.0f / 2048.0f)

typedef unsigned short u16;
typedef unsigned int   u32;
typedef unsigned char  u8;
typedef __attribute__((ext_vector_type(4))) int   i32x4;
typedef __attribute__((ext_vector_type(8))) int   i32x8;
typedef __attribute__((ext_vector_type(4))) float f32x4;
typedef __attribute__((ext_vector_type(2))) float f32x2;

// ---------------------------------------------------------------------------
// Fragment-major fp8 layout (validated R3/R6: zero bank conflicts in GEMM
// main loops). A [R][K] matrix is stored as 2KB sub-tiles:
//   off(r,k) = (rt*(K/128) + kt)*2048 + h*1024 + (16*q + rr)*16 + b
//   rt=r>>4, rr=r&15, kt=k>>7, q=(k>>5)&3, h=(k>>4)&1, b=k&15
// = exactly the mfma_scale_f32_16x16x128 operand order: lane (16q+rr) reads
// lo 16B at lane*16 and hi 16B at lane*16+1024 within a sub-tile. Staging is
// a LINEAR copy; every frag ds_read_b128 is 64 lanes x 16B contiguous.
// ---------------------------------------------------------------------------

__device__ __forceinline__ u32 pk4_fp8(float a, float b, float c, float d) {
  u32 u = 0;
  u = __builtin_amdgcn_cvt_pk_fp8_f32(a, b, u, false);
  u = __builtin_amdgcn_cvt_pk_fp8_f32(c, d, u, true);
  return u;
}
__device__ __forceinline__ u8 f8(float v) {
  return (u8)(__builtin_amdgcn_cvt_pk_fp8_f32(v, v, 0, false) & 0xff);
}

__device__ __forceinline__ void async16(const void* g, void* l) {
  __builtin_amdgcn_global_load_lds(
      (const __attribute__((address_space(1))) void*)g,
      (__attribute__((address_space(3))) void*)l, 16, 0, 0);
}

// ---------------- conversion kernels ----------------

// xs fp32 [4096][8192] -> fp8 fragment-major. One block = one 2KB sub-tile
// (16 rows x 128 k). Reads coalesced, writes contiguous 2KB.
__global__ void convert_xs(const float* __restrict__ xs, u8* __restrict__ out) {
  __shared__ float t16[16][132];   // +4 pad: stagger banks for the read phase
  const int bid = blockIdx.x;      // 0..16383
  const int rt = bid >> 6, kt = bid & 63;
  const int tid = threadIdx.x;     // 256
  const float* src = xs + (size_t)rt * 16 * K_IN + kt * 128;
#pragma unroll
  for (int j = 0; j < 2; ++j) {
    int i = tid + j * 256;         // 0..511 float4s
    int row = i >> 5, c4 = (i & 31) << 2;
    float4 v = *(const float4*)(src + (size_t)row * K_IN + c4);
    t16[row][c4 + 0] = v.x; t16[row][c4 + 1] = v.y;
    t16[row][c4 + 2] = v.z; t16[row][c4 + 3] = v.w;
  }
  __syncthreads();
  const int cw = tid >> 1, part = tid & 1;
  const int h = cw >> 6, l = cw & 63, q = l >> 4, rr = l & 15;
  const float* p = &t16[rr][q * 32 + h * 16 + part * 8];
  u32 u0 = pk4_fp8(p[0], p[1], p[2], p[3]);
  u32 u1 = pk4_fp8(p[4], p[5], p[6], p[7]);
  uint2 st = {u0, u1};
  *(uint2*)(out + ((size_t)(rt * 64 + kt) << 11) + cw * 16 + part * 8) = st;
}

// W [K_IN, F_DIM] fp32 -> Wt fragment-major [F_DIM rows, K_IN], scaled x64
// (w~0.011 would be subnormal in e4m3; 2^-6 undone via MFMA B-scale 121).
// Packed through LDS so global writes are contiguous 16B.
__global__ void transpose_w(const float* __restrict__ W, u8* __restrict__ Wt) {
  __shared__ float tile[128][33];
  __shared__ u32 ob[1024];         // 4KB packed output (2 sub-tiles)
  int k0 = blockIdx.x * 128;       // over K_IN/128
  int f0 = blockIdx.y * 32;        // over F_DIM/32
  int tx = threadIdx.x, ty = threadIdx.y;   // (32, 8)
#pragma unroll
  for (int kk = 0; kk < 16; ++kk) {
    int k = kk * 8 + ty;
    tile[k][tx] = 64.0f * W[(size_t)(k0 + k) * F_DIM + f0 + tx];
  }
  __syncthreads();
#pragma unroll
  for (int ff = 0; ff < 4; ++ff) {
    int f = ff * 8 + ty;
    int kk = tx * 4;
    u32 p = pk4_fp8(tile[kk][f], tile[kk + 1][f], tile[kk + 2][f], tile[kk + 3][f]);
    int rtl = f >> 4, rr = f & 15;
    int q = kk >> 5, hh = (kk >> 4) & 1;
    ob[rtl * 512 + hh * 256 + (q * 16 + rr) * 4 + ((kk & 15) >> 2)] = p;
  }
  __syncthreads();
  const int t = ty * 32 + tx;      // 0..255
  const int kt = k0 >> 7, rt0 = f0 >> 4;
  uint4* dst = (uint4*)(Wt + ((size_t)((rt0 + (t >> 7)) * 64 + kt) << 11));
  dst[t & 127] = ((const uint4*)ob)[t];
}

// beta[i] = alpha[i] * (2*y[i]-1); out[0] = -sum(alpha)
__global__ void prep(const float* __restrict__ alphas, const int* __restrict__ ys,
                     float* __restrict__ beta, float* __restrict__ out) {
  __shared__ float red[1024];
  int t = threadIdx.x;
  float s = 0.f;
  for (int i = t; i < N_ROWS; i += 1024) {
    float a = alphas[i];
    beta[i] = a * (float)(2 * ys[i] - 1);
    s += a;
  }
  red[t] = s;
  __syncthreads();
  for (int off = 512; off; off >>= 1) {
    if (t < off) red[t] += red[t + off];
    __syncthreads();
  }
  if (t == 0) out[0] = -red[0];
}

// sq[i] = sum_f dequant(X_fp8[i][f])^2 from the SAME quantized X the gram
// MFMA consumes (so d2_ii == 0 exactly). X is fragment-major [4096 r][2048 k].
__global__ void row_sq(const u32* __restrict__ X, float* __restrict__ sq) {
  int wave = threadIdx.x >> 6, lane = threadIdx.x & 63;
  int row = blockIdx.x * 4 + wave;
  const u8* base = (const u8*)X + ((size_t)(row >> 4) << 15);  // rt*16*2048
  const int rr = row & 15;
  float s = 0.f;
#pragma unroll
  for (int it = 0; it < 2; ++it) {
    int c = lane + it * 64;                 // 16B chunk id, 128 chunks/row
    int kt = c >> 3, q = (c >> 1) & 3, h = c & 1;
    uint4 v = *(const uint4*)(base + kt * 2048 + h * 1024 + (q * 16 + rr) * 16);
    u32 w[4] = {v.x, v.y, v.z, v.w};
#pragma unroll
    for (int p = 0; p < 4; ++p) {
      f32x2 lo = __builtin_amdgcn_cvt_pk_f32_fp8(w[p], false);
      f32x2 hi = __builtin_amdgcn_cvt_pk_f32_fp8(w[p], true);
      s += lo[0] * lo[0] + lo[1] * lo[1] + hi[0] * hi[0] + hi[1] * hi[1];
    }
  }
#pragma unroll
  for (int off = 32; off; off >>= 1) s += __shfl_down(s, off);
  if (lane == 0) sq[row] = s;
}

// ---- GEMM1 (R3 structure — best measured): 256x128 tile, 512 thr, in-block
// split-K (2 halves x 4 waves), wave-tile 128x64. A single-buffered 32KB +
// B double-buffered 2x16KB per half = 128KB LDS. 2-phase loop {read af;
// barrier; stage kt+1 under MFMA; barrier}. grid=256 (1/CU), 2 waves/SIMD.
// R7 changes vs R3: (a) merge epilogue uses lane-contiguous slot layout
// (R4 measured 3.8M conflict-cycles ~6us on the strided layout);
// (b) setprio(1) around the 32-MFMA cluster.
__global__ __launch_bounds__(512, 2) void gemm_xw(const u8* __restrict__ A,
                                                  const u8* __restrict__ Bt,
                                                  u8* __restrict__ X) {
  __shared__ __align__(16) u8 smem[131072];
  const int tid = threadIdx.x;
  // XCD-chunked swizzle: each XCD's 32 blocks cover 2 n-panels (2MB Wt ->
  // L2-resident) x all 16 m-tiles.
  const int wg = blockIdx.x;
  const int L = (wg & 7) * 32 + (wg >> 3);
  const int m0 = (L & 15) << 8;   // 16 m-tiles of 256
  const int n0 = (L >> 4) << 7;   // 16 n-tiles of 128

  const int lane = tid & 63;
  const int wave = tid >> 6;      // 0..7
  const int kh = wave >> 2;       // K-half: waves 0-3 -> k[0,4096), 4-7 -> rest
  const int w2 = wave & 3;
  const int wm = (w2 >> 1) << 7;  // 0 / 128
  const int wn = (w2 & 1) << 6;   // 0 / 64
  const int t = tid & 255;        // thread id within half

  u8* sA  = smem + kh * 65536;          // 32KB, single-buffered
  u8* sB0 = sA + 32768;                 // 16KB
  u8* sB1 = sB0 + 16384;                // 16KB

  const u8* pA = A  + (size_t)((m0 >> 4) + (t >> 7)) * 131072 + (t & 127) * 16;
  const u8* pB = Bt + (size_t)((n0 >> 4) + (t >> 7)) * 131072 + (t & 127) * 16;
  const int oT = t * 16;

  f32x4 acc[8][4];
  const f32x4 zero = {0.f, 0.f, 0.f, 0.f};
#pragma unroll
  for (int i = 0; i < 8; ++i)
#pragma unroll
    for (int j = 0; j < 4; ++j) acc[i][j] = zero;

#define STAGE_A(KT) { _Pragma("unroll") for (int j_ = 0; j_ < 8; ++j_) \
    async16(pA + (size_t)j_ * 262144 + (size_t)(KT) * 2048, sA + oT + j_ * 4096); }
#define STAGE_B(BUF, KT) { _Pragma("unroll") for (int j_ = 0; j_ < 4; ++j_) \
    async16(pB + (size_t)j_ * 262144 + (size_t)(KT) * 2048, (BUF) + oT + j_ * 4096); }
#define MFMA1(MT, NT, AF, BG) \
    acc[MT][NT] = __builtin_amdgcn_mfma_scale_f32_16x16x128_f8f6f4( \
        AF, BG, acc[MT][NT], 0, 0, 0, 127, 0, 121);

  const int kbase = kh * 32;      // this half's first k-tile (of 64)
  STAGE_A(kbase)
  STAGE_B(sB0, kbase)
  __syncthreads();                // vmcnt(0): tile kbase visible

  const int aB = lane * 16;
  const int sa0 = wm >> 4;        // A sub base: 0 or 8
  const int sb0i = wn >> 4;       // B sub base: 0 or 4

  for (int it = 0; it < 32; ++it) {
    const int kt = kbase + it;
    u8* sBc = (it & 1) ? sB1 : sB0;
    u8* sBn = (it & 1) ? sB0 : sB1;

    // phase 1: pull ALL A frags into regs (A is single-buffered)
    i32x8 af[8];
#pragma unroll
    for (int mt = 0; mt < 8; ++mt) {
      const u8* b_ = sA + (sa0 + mt) * 2048 + aB;
      i32x4 lo = *(const i32x4*)(b_);
      i32x4 hi = *(const i32x4*)(b_ + 1024);
      af[mt] = (i32x8){lo[0], lo[1], lo[2], lo[3], hi[0], hi[1], hi[2], hi[3]};
    }
    __syncthreads();              // af in regs; A + B[cur] consumed-enough

    // phase 2: stage kt+1 (A and B-next) under the MFMA cluster
    if (it < 31) { STAGE_A(kt + 1) STAGE_B(sBn, kt + 1) }
    __builtin_amdgcn_s_setprio(1);
#pragma unroll
    for (int nt = 0; nt < 4; ++nt) {
      const u8* b_ = sBc + (sb0i + nt) * 2048 + aB;
      i32x4 lo = *(const i32x4*)(b_);
      i32x4 hi = *(const i32x4*)(b_ + 1024);
      i32x8 bg = (i32x8){lo[0], lo[1], lo[2], lo[3], hi[0], hi[1], hi[2], hi[3]};
      MFMA1(0, nt, af[0], bg) MFMA1(1, nt, af[1], bg)
      MFMA1(2, nt, af[2], bg) MFMA1(3, nt, af[3], bg)
      MFMA1(4, nt, af[4], bg) MFMA1(5, nt, af[5], bg)
      MFMA1(6, nt, af[6], bg) MFMA1(7, nt, af[7], bg)
    }
    __builtin_amdgcn_s_setprio(0);
    __syncthreads();              // vmcnt(0): kt+1 landed (covered by MFMAs)
  }
#undef STAGE_A
#undef STAGE_B
#undef MFMA1

  // merge K-halves through LDS, then quantize + store (fragment-major X).
  // R7: slot s = (mt*4+nt)*256 + t -> 64 lanes write/read CONTIGUOUS 16B
  // (old layout strided 512B/lane: 16-way bank conflict, 3.8M cyc measured).
  __syncthreads();
  float* red = (float*)smem;      // 32 slots x 256 t x 16B = 128KB
  if (kh == 1) {
#pragma unroll
    for (int mt = 0; mt < 8; ++mt)
#pragma unroll
      for (int nt = 0; nt < 4; ++nt)
        *(f32x4*)(red + ((size_t)(mt * 4 + nt) * 256 + t) * 4) = acc[mt][nt];
  }
  __syncthreads();
  if (kh == 0) {
    const int q = lane >> 4, r = lane & 15;
    const int qq0 = wn >> 5;      // 0 or 2
#pragma unroll
    for (int mt = 0; mt < 8; ++mt) {
#pragma unroll
      for (int nt = 0; nt < 4; ++nt) {
        f32x4 v = acc[mt][nt] + *(const f32x4*)(red + ((size_t)(mt * 4 + nt) * 256 + t) * 4);
        const int rt = (m0 >> 4) + (wm >> 4) + mt;
        const int qq = qq0 + (nt >> 1);
        const int hh = nt & 1;
        u8* dst = X + (size_t)rt * 32768 + (size_t)(n0 >> 7) * 2048 + hh * 1024 + r;
#pragma unroll
        for (int e = 0; e < 4; ++e)
          dst[(qq * 16 + ((q << 2) + e)) * 16] = f8(v[e]);
      }
    }
  }
}

// ------- gram GEMM core on fragment-major X: 128x128 tile, 2-barrier loop
// (R3 version — 3 blocks/CU multi-block asynchrony beat the 2-blk/CU
// pipelined variant by ~5us in the R3 vs R6 A/B) -------
__device__ __forceinline__ void gemm_tile_x(const u8* __restrict__ X, int m0, int n0,
                                            u8* sA, u8* sB, int tid, f32x4 acc[4][4]) {
  const int lane = tid & 63;
  const int wave = tid >> 6;
  const f32x4 zero = {0.f, 0.f, 0.f, 0.f};
#pragma unroll
  for (int mt = 0; mt < 4; ++mt)
#pragma unroll
    for (int nt = 0; nt < 4; ++nt) acc[mt][nt] = zero;

  // staging (linear copy; X sub-stride = 16*2048 = 32768, 16 k-tiles)
  const u8* pA = X + (size_t)((m0 >> 4) + (tid >> 7)) * 32768 + (tid & 127) * 16;
  const u8* pB = X + (size_t)((n0 >> 4) + (tid >> 7)) * 32768 + (tid & 127) * 16;
  const int oT = tid * 16;
  const int aB = lane * 16;
  const int sa0 = (wave >> 1) * 4, sb0 = (wave & 1) * 4;

  for (int kt = 0; kt < 16; ++kt) {
#pragma unroll
    for (int j = 0; j < 4; ++j) {
      async16(pA + (size_t)j * 65536 + kt * 2048, sA + oT + j * 4096);
      async16(pB + (size_t)j * 65536 + kt * 2048, sB + oT + j * 4096);
    }
    __syncthreads();   // drains vmcnt -> staged data visible

    i32x8 af[4], bg[4];
#pragma unroll
    for (int mt = 0; mt < 4; ++mt) {
      const u8* b_ = sA + (sa0 + mt) * 2048 + aB;
      i32x4 lo = *(const i32x4*)(b_);
      i32x4 hi = *(const i32x4*)(b_ + 1024);
      af[mt] = (i32x8){lo[0], lo[1], lo[2], lo[3], hi[0], hi[1], hi[2], hi[3]};
    }
#pragma unroll
    for (int nt = 0; nt < 4; ++nt) {
      const u8* b_ = sB + (sb0 + nt) * 2048 + aB;
      i32x4 lo = *(const i32x4*)(b_);
      i32x4 hi = *(const i32x4*)(b_ + 1024);
      bg[nt] = (i32x8){lo[0], lo[1], lo[2], lo[3], hi[0], hi[1], hi[2], hi[3]};
    }
    __builtin_amdgcn_s_setprio(1);
#pragma unroll
    for (int mt = 0; mt < 4; ++mt)
#pragma unroll
      for (int nt = 0; nt < 4; ++nt)
        acc[mt][nt] = __builtin_amdgcn_mfma_scale_f32_16x16x128_f8f6f4(
            af[mt], bg[nt], acc[mt][nt], 0, 0, 0, 127, 0, 127);
    __builtin_amdgcn_s_setprio(0);
    __syncthreads();
  }
}

// GEMM2 (triangular) + fused RBF epilogue + reduction
__global__ __launch_bounds__(256, 3) void gemm_kern(const u8* __restrict__ X,
                                                    const float* __restrict__ sq,
                                                    const float* __restrict__ beta,
                                                    float* __restrict__ out) {
  __shared__ __align__(16) u8 sA[128 * 128];
  __shared__ __align__(16) u8 sB[128 * 128];
  const int tid = threadIdx.x;
  int bid = blockIdx.x;
  int ib = 0;
  while (bid >= 32 - ib) { bid -= 32 - ib; ++ib; }
  const int jb = ib + bid;
  const int m0 = ib << 7;
  const int n0 = jb << 7;

  f32x4 acc[4][4];
  gemm_tile_x(X, m0, n0, sA, sB, tid, acc);

  const int lane = tid & 63;
  const int q = lane >> 4;
  const int r = lane & 15;
  const int wave = tid >> 6;
  const int wm = (wave >> 1) << 6;
  const int wn = (wave & 1) << 6;

  float sqj[4], bj[4];
#pragma unroll
  for (int nt = 0; nt < 4; ++nt) {
    int j = n0 + wn + (nt << 4) + r;
    sqj[nt] = sq[j];
    bj[nt] = beta[j];
  }
  float local = 0.f;
#pragma unroll
  for (int mt = 0; mt < 4; ++mt) {
#pragma unroll
    for (int e = 0; e < 4; ++e) {
      int i = m0 + wm + (mt << 4) + (q << 2) + e;
      float sqi = sq[i];
      float bi = beta[i];
#pragma unroll
      for (int nt = 0; nt < 4; ++nt) {
        float d2 = fmaxf(sqi + sqj[nt] - 2.f * acc[mt][nt][e], 0.f);
        local += bi * bj[nt] * __expf(-GAMMA * d2);
      }
    }
  }
  // diag blocks once (x0.5 for the 0.5*quad form), off-diag twice (x1.0)
  local *= (ib == jb) ? 0.5f : 1.0f;
#pragma unroll
  for (int off = 32; off; off >>= 1) local += __shfl_down(local, off);
  if (lane == 0) atomicAdd(out, local);
}

// ---------------- launch ----------------

extern "C" void kernel_launch(void* const* d_in, const int* in_sizes, int n_in,
                              void* d_out, int out_size, void* d_ws, size_t ws_size,
                              hipStream_t stream) {
  const float* xs = (const float*)d_in[0];
  const float* W = (const float*)d_in[1];
  const int* ys = (const int*)d_in[2];
  const float* alphas = (const float*)d_in[3];
  float* out = (float*)d_out;

  char* ws = (char*)d_ws;
  u8* xs_f8 = (u8*)ws;                        //  32 MB: [4096, 8192] fp8 frag-major
  u8* Wt_f8 = (u8*)(ws + 33554432);           //  16 MB: [2048, 8192] fp8 frag-major (x64)
  u8* X_f8  = (u8*)(ws + 50331648);           //   8 MB: [4096, 2048] fp8 frag-major
  float* sq   = (float*)(ws + 58720256);      //  16 KB
  float* beta = (float*)(ws + 58736640);      //  16 KB

  convert_xs<<<16384, 256, 0, stream>>>(xs, xs_f8);
  dim3 tb(32, 8);
  dim3 tg(K_IN / 128, F_DIM / 32);
  transpose_w<<<tg, tb, 0, stream>>>(W, Wt_f8);
  prep<<<1, 1024, 0, stream>>>(alphas, ys, beta, out);

  gemm_xw<<<256, 512, 0, stream>>>(xs_f8, Wt_f8, X_f8);
  row_sq<<<N_ROWS / 4, 256, 0, stream>>>((const u32*)X_f8, sq);
  gemm_kern<<<528, 256, 0, stream>>>(X_f8, sq, beta, out);
}